// Round 7
// baseline (671.786 us; speedup 1.0000x reference)
//
#include <hip/hip_runtime.h>
#include <cstdint>
#include <cstddef>

// Problem constants (fixed by reference)
#define BATCH 32
#define SEQ   2048
#define DIM   1024      // ENC_D = DEC_D = ATTN_D = OUT_D = 1024
#define MROWS (BATCH*SEQ)   // 65536

typedef __attribute__((ext_vector_type(4))) float  floatx4;
typedef __attribute__((ext_vector_type(8))) short  short8;

// fp32 -> bf16 round-to-nearest-even
__device__ __forceinline__ unsigned short f2bf(float f) {
  unsigned int u = __float_as_uint(f);
  u += 0x7fffu + ((u >> 16) & 1u);
  return (unsigned short)(u >> 16);
}

// async global->LDS, 16B per lane; LDS dest = wave-uniform base + lane*16
__device__ __forceinline__ void async16(const void* g, void* l) {
  __builtin_amdgcn_global_load_lds(
      (const __attribute__((address_space(1))) unsigned int*)g,
      (__attribute__((address_space(3))) unsigned int*)l, 16, 0, 0);
}

__device__ __forceinline__ float fast_tanh(float x) {
  float e = __expf(2.0f * x);
  return 1.0f - 2.0f * __builtin_amdgcn_rcpf(1.0f + e);
}

// ---------------------------------------------------------------------------
// Kernel P: fused prep = transpose + dech (convert is now fused INTO the GEMM).
//   [0,1024)    : Wt[n][k] = bf16(W_enc[k][n])
//   [1024,1152) : dech[b][a] += dec[b]z @ W_dec z (8 batches/block, splitK x8)
// ---------------------------------------------------------------------------
__global__ void k_prep(const float* __restrict__ W_enc, unsigned short* __restrict__ Wt,
                       const float* __restrict__ dec, const float* __restrict__ W_dec,
                       const float* __restrict__ b_dec, const float* __restrict__ b_enc,
                       float* __restrict__ dech) {
  __shared__ float tile[32][33];
  int blk = blockIdx.x;
  int tid = threadIdx.x;
  if (blk < 1024) {
    // ---- transpose W_enc -> Wt (32x32 tiles) ----
    int n0 = (blk & 31) * 32, k0 = (blk >> 5) * 32;
    int tx = tid & 31, ty = tid >> 5;   // (32, 8)
#pragma unroll
    for (int i = 0; i < 4; ++i) {
      int y = ty + i * 8;
      tile[y][tx] = W_enc[(size_t)(k0 + y) * DIM + n0 + tx];
    }
    __syncthreads();
#pragma unroll
    for (int i = 0; i < 4; ++i) {
      int y = ty + i * 8;
      Wt[(size_t)(n0 + y) * DIM + k0 + tx] = f2bf(tile[tx][y]);
    }
  } else {
    // ---- dech: 8 batches/block, split-K x8; z==0 adds biases ----
    int db = blk - 1024;
    int ax = db & 3, bgi = (db >> 2) & 3, z = db >> 4;
    int a  = ax * 256 + tid;
    int bg = bgi * 8;
    float bias = (z == 0) ? (b_dec[a] + b_enc[a]) : 0.0f;
    float acc[8];
#pragma unroll
    for (int j = 0; j < 8; ++j) acc[j] = bias;
    const float* wcp = W_dec + (size_t)z * 128 * DIM + a;
#pragma unroll 4
    for (int e = 0; e < 128; ++e) {
      float w = wcp[(size_t)e * DIM];
#pragma unroll
      for (int j = 0; j < 8; ++j)
        acc[j] = fmaf(dec[(size_t)(bg + j) * DIM + z * 128 + e], w, acc[j]);
    }
#pragma unroll
    for (int j = 0; j < 8; ++j)
      atomicAdd(&dech[(size_t)(bg + j) * DIM + a], acc[j]);
  }
}

// ---------------------------------------------------------------------------
// Kernel 3: 256x256-tile 8-phase GEMM + fused fp32->bf16 A-conversion +
// tanh-dot epilogue.
//   score[m] += sum_n tanh( (enc@W_enc)[m][n] + dech[b(m)][n] ) * w_attn[n]
// BM=BN=256, BK=64, 512 thr = 8 waves (2M x 4N), per-wave 128x64 out.
// LDS 128 KB: A bufs @ 0/32K, B bufs @ 64K/96K; 128 B per row (64 bf16).
// Swizzle: physical = logical ^ (((logical>>7)&7)<<4) (16B-granular involution).
//
// R7 FUSED A-STAGING (kills the 384 MB convert pass):
//   A is REG-staged from fp32 enc: ph1 issues A(t+2):h0 loads (4 dwordx4/lane),
//   ph2 h1, ph3 B(t+2) via global_load_lds (FIFO: A-h0 < A-h1 < B), ph4
//   VMCNT(4) -> cvt(f2bf x16) -> 4x ds_write_b128 into dead CUR.A.
//   ds_write is per-lane, so the LDS dest is LINEAR and the swizzle moves
//   into the GLOBAL fp32 address (lane fetches logical L(P) = P ^ swz):
//     row(P) unchanged by swz; col16(P) -> col16 ^ (lane>>3).
//   B staging unchanged (pre-swizzled Wt source, linear gload_lds dest).
// Wait math (per-wave load units of 4): entering t: [B(t+1)]; ph1 +Ah0;
//   ph2 +Ah1; ph3 +B(t+2); ph4 VMCNT(4) retires B(t+1),Ah0,Ah1 (B(t+1) is
//   read at t+1.ph1; A written now), leaves B(t+2) in flight. Never drains.
// Write visibility: LGKM is in-order; the ph4 read-ahead's compiler lgkm
//   wait (before t+1.ph1 MFMA) drains the ds_writes; readers of A(t+2) are
//   at t+2.ph1, >=4 barriers later. Prologue needs one explicit lgkmcnt(0).
// Tail: t13 stages A(15)/B(15); t14 MODE1 VMCNT(0); t15 MODE2 nothing.
// ---------------------------------------------------------------------------
#define PH_BAR do { asm volatile("" ::: "memory"); __builtin_amdgcn_s_barrier(); asm volatile("" ::: "memory"); } while(0)
#define SCHED0 __builtin_amdgcn_sched_barrier(0)
#define SP1 __builtin_amdgcn_s_setprio(1)
#define SP0 __builtin_amdgcn_s_setprio(0)
#define VMCNT(n) asm volatile("s_waitcnt vmcnt(" #n ")" ::: "memory")
#define LGKM0 asm volatile("s_waitcnt lgkmcnt(0)" ::: "memory")

__global__ void __launch_bounds__(512, 2) k_gemm256(
    const float* __restrict__ enc,          // [65536,1024] fp32
    const unsigned short* __restrict__ Wt,  // [1024 n][1024 k] bf16
    const float* __restrict__ dech,         // [32,1024]
    const float* __restrict__ w_attn,       // [1024]
    const int* __restrict__ enc_len,        // [32]
    float* __restrict__ score)              // [65536], pre-zeroed
{
  int bid = blockIdx.x;                 // 1024 blocks
  int t  = (bid & 7) * 128 + (bid >> 3); // bijective XCD swizzle (1024%8==0)
  int nb = t & 3;                        // col tile (n0 = nb*256); 4 nb share rt on one XCD
  int rt = t >> 2;                       // row tile 0..255 (m0 = rt*256)
  int bb = rt >> 3;                      // batch (8 row-tiles per batch)
  int len = enc_len[bb];
  if (((rt & 7) * 256) >= len) return;   // fully masked tile

  __shared__ __align__(16) char lds[131072];

  int tid = threadIdx.x;
  int w = tid >> 6, lane = tid & 63;
  int wr = w >> 2;               // 0..1  M-warp
  int wc = w & 3;                // 0..3  N-warp
  int li = lane & 15, g = lane >> 4;
  int xl = (li & 7) << 4;        // lane-constant read swizzle

  const char* Agc = (const char*)enc + (size_t)rt * 256 * 4096;  // fp32 A tile
  const char* Bg  = (const char*)(Wt + (size_t)nb * 256 * DIM);

  // B stage: pre-swizzled global source (bf16), linear LDS dest (unchanged)
  size_t sbase = (size_t)((lane >> 3) * 2048 +
                 (((lane & 7) << 4) ^ (((lane >> 3) & 7) << 4)));
  size_t swoff = (size_t)(w * 2) * 16384;
  int    ldbase = w * 2048;

#define STAGE_B(buf, h, kt) do { \
  async16(Bg + sbase + swoff + (size_t)(h) * 262144 + (size_t)(kt) * 128, \
          lds + 65536 + (buf) * 32768 + ldbase + (h) * 16384); \
  async16(Bg + sbase + swoff + 16384 + (size_t)(h) * 262144 + (size_t)(kt) * 128, \
          lds + 65536 + (buf) * 32768 + ldbase + 1024 + (h) * 16384); \
} while (0)

  // A reg-stage: lane owns physical 16B chunks P = h*16384 + w*2048 + c*1024
  // + lane*16; fetches logical L = P ^ ((lane>>3)<<4) as fp32 (32 B = 2 float4)
  size_t aoff = (size_t)(w * 16 + (lane >> 3)) * 4096 +
                (size_t)(((lane & 7) ^ (lane >> 3)) * 32);
  float4 aR[2][2][2];   // [h][c][j] -- 32 VGPR, live ph1..ph4 within a tile

#define LOAD_A(kt) do { \
  _Pragma("unroll") for (int c = 0; c < 2; ++c) { \
    const char* g0_ = Agc + aoff + (size_t)(c * 8) * 4096 + (size_t)(kt) * 256; \
    aR[0][c][0] = *(const float4*)(g0_); \
    aR[0][c][1] = *(const float4*)(g0_ + 16); \
  } \
} while (0)
#define LOAD_A1(kt) do { \
  _Pragma("unroll") for (int c = 0; c < 2; ++c) { \
    const char* g1_ = Agc + aoff + (size_t)(128 + c * 8) * 4096 + (size_t)(kt) * 256; \
    aR[1][c][0] = *(const float4*)(g1_); \
    aR[1][c][1] = *(const float4*)(g1_ + 16); \
  } \
} while (0)
#define WRITE_A(buf) do { \
  _Pragma("unroll") for (int h_ = 0; h_ < 2; ++h_) \
  _Pragma("unroll") for (int c_ = 0; c_ < 2; ++c_) { \
    float4 u0_ = aR[h_][c_][0], u1_ = aR[h_][c_][1]; \
    short8 pk_; \
    pk_[0] = (short)f2bf(u0_.x); pk_[1] = (short)f2bf(u0_.y); \
    pk_[2] = (short)f2bf(u0_.z); pk_[3] = (short)f2bf(u0_.w); \
    pk_[4] = (short)f2bf(u1_.x); pk_[5] = (short)f2bf(u1_.y); \
    pk_[6] = (short)f2bf(u1_.z); pk_[7] = (short)f2bf(u1_.w); \
    *(short8*)(lds + (buf) * 32768 + h_ * 16384 + w * 2048 + c_ * 1024 + lane * 16) = pk_; \
  } \
} while (0)

  short8 sA0[2][2], sA1[2][2];   // rotating A f01 / B1 slots
  short8 aX[2][2];               // A high frag-pair of current half
  short8 bX[2][2];               // B0
  floatx4 acc[8][4] = {};        // 8 m-frags x 4 n-frags

#define RD_A2(buf, f0, DST) do { \
  const char* base_ = lds + (buf) * 32768 + (wr * 128 + (f0) * 16 + li) * 128; \
  int c0_ = (g * 16) ^ xl; \
  _Pragma("unroll") for (int j = 0; j < 2; ++j) { \
    DST[j][0] = *(const short8*)(base_ + j * 2048 + c0_); \
    DST[j][1] = *(const short8*)(base_ + j * 2048 + (c0_ ^ 64)); \
  } \
} while (0)
#define RD_B(buf, nh, DST) do { \
  const char* base_ = lds + 65536 + (buf) * 32768 + (wc * 64 + (nh) * 32 + li) * 128; \
  int c0_ = (g * 16) ^ xl; \
  _Pragma("unroll") for (int tnq = 0; tnq < 2; ++tnq) { \
    DST[tnq][0] = *(const short8*)(base_ + tnq * 2048 + c0_); \
    DST[tnq][1] = *(const short8*)(base_ + tnq * 2048 + (c0_ ^ 64)); \
  } \
} while (0)
#define MFMA_Q(mh, nh, ALO, AHI, BB) do { \
  _Pragma("unroll") for (int ks = 0; ks < 2; ++ks) \
  _Pragma("unroll") for (int tnq = 0; tnq < 2; ++tnq) { \
    acc[(mh)*4+0][(nh)*2+tnq] = __builtin_amdgcn_mfma_f32_16x16x32_bf16(ALO[0][ks], BB[tnq][ks], acc[(mh)*4+0][(nh)*2+tnq], 0, 0, 0); \
    acc[(mh)*4+1][(nh)*2+tnq] = __builtin_amdgcn_mfma_f32_16x16x32_bf16(ALO[1][ks], BB[tnq][ks], acc[(mh)*4+1][(nh)*2+tnq], 0, 0, 0); \
    acc[(mh)*4+2][(nh)*2+tnq] = __builtin_amdgcn_mfma_f32_16x16x32_bf16(AHI[0][ks], BB[tnq][ks], acc[(mh)*4+2][(nh)*2+tnq], 0, 0, 0); \
    acc[(mh)*4+3][(nh)*2+tnq] = __builtin_amdgcn_mfma_f32_16x16x32_bf16(AHI[1][ks], BB[tnq][ks], acc[(mh)*4+3][(nh)*2+tnq], 0, 0, 0); \
  } \
} while (0)

// MODE 0: steady. MODE 1: tile NT-2 (no staging, VMCNT(0) at ph4).
// MODE 2: last tile (nothing).
#define TILE_STEP(CUR, KT2, MODE, SP_, SQ_) do { \
  /* ph1: Q(0,0); issue A(t+2):h0 fp32 loads */ \
  RD_A2(CUR, 2, aX); \
  RD_B(CUR, 0, bX); \
  if ((MODE) == 0) { LOAD_A(KT2); } \
  PH_BAR; SCHED0; SP1; MFMA_Q(0, 0, SP_, aX, bX); SP0; SCHED0; \
  PH_BAR; \
  /* ph2: Q(0,1); issue A(t+2):h1 loads */ \
  RD_B(CUR, 1, SQ_); \
  if ((MODE) == 0) { LOAD_A1(KT2); } \
  PH_BAR; SCHED0; SP1; MFMA_Q(0, 1, SP_, aX, SQ_); SP0; SCHED0; \
  PH_BAR; \
  /* ph3: Q(1,1); CUR.B dead -> glds B(t+2) (FIFO after A loads) */ \
  if ((MODE) == 0) { STAGE_B(CUR, 0, KT2); STAGE_B(CUR, 1, KT2); } \
  RD_A2(CUR, 4, SP_); \
  RD_A2(CUR, 6, aX); \
  PH_BAR; SCHED0; SP1; MFMA_Q(1, 1, SP_, aX, SQ_); SP0; SCHED0; \
  PH_BAR; \
  /* ph4: Q(1,0); CUR.A dead -> cvt+ds_write A(t+2); read-ahead A(t+1) f01 */ \
  if ((MODE) == 0) { VMCNT(4); WRITE_A(CUR); } \
  else if ((MODE) == 1) { VMCNT(0); } \
  if ((MODE) < 2) RD_A2((CUR) ^ 1, 0, SQ_); \
  PH_BAR; SCHED0; SP1; MFMA_Q(1, 0, SP_, aX, bX); SP0; SCHED0; \
  PH_BAR; \
} while (0)

  // prologue: A(0) via regs -> buf0; then [A(1) loads, B(0), B(1)] with
  // VMCNT(4) leaving B(1) in flight (steady invariant [B(t+1)]).
  LOAD_A(0); LOAD_A1(0);
  VMCNT(0);
  WRITE_A(0);
  LOAD_A(1); LOAD_A1(1);
  STAGE_B(0, 0, 0); STAGE_B(0, 1, 0);
  STAGE_B(1, 0, 1); STAGE_B(1, 1, 1);
  VMCNT(4);          // retires A(1) loads + B(0); leaves B(1)
  WRITE_A(1);
  LGKM0;             // publish A writes before the barrier (cross-wave)
  PH_BAR;
  RD_A2(0, 0, sA0);  // tile0 f01

  // main: tiles 0..13 stage tiles 2..15 (NT=16); slot roles swap per tile
#pragma unroll 1
  for (int u = 0; u < 14; u += 2) {
    TILE_STEP(0, u + 2, 0, sA0, sA1);
    TILE_STEP(1, u + 3, 0, sA1, sA0);
  }
  TILE_STEP(0, 0, 1, sA0, sA1);   // tile 14
  TILE_STEP(1, 0, 2, sA1, sA0);   // tile 15

  // epilogue: C/D layout col=lane&15 (n), row=(lane>>4)*4+reg (m)  [m89]
  float dh[4], wa[4];
#pragma unroll
  for (int tn = 0; tn < 4; ++tn) {
    int n = nb * 256 + wc * 64 + tn * 16 + li;
    dh[tn] = dech[(size_t)bb * DIM + n];
    wa[tn] = w_attn[n];
  }
#pragma unroll
  for (int tm = 0; tm < 8; ++tm) {
    int mrow = rt * 256 + wr * 128 + tm * 16 + g * 4;
#pragma unroll
    for (int r = 0; r < 4; ++r) {
      float v = 0.0f;
#pragma unroll
      for (int tn = 0; tn < 4; ++tn)
        v = fmaf(wa[tn], fast_tanh(acc[tm][tn][r] + dh[tn]), v);
      v += __shfl_xor(v, 1);
      v += __shfl_xor(v, 2);
      v += __shfl_xor(v, 4);
      v += __shfl_xor(v, 8);
      if (li == 0) atomicAdd(&score[mrow + r], v);
    }
  }
#undef TILE_STEP
#undef MFMA_Q
#undef RD_B
#undef RD_A2
#undef WRITE_A
#undef LOAD_A1
#undef LOAD_A
#undef STAGE_B
}

// ---------------------------------------------------------------------------
// Kernel 4: masked softmax per batch row. SCALING == 1.0 (folded out).
// ---------------------------------------------------------------------------
__global__ void k_softmax(const float* __restrict__ score, const int* __restrict__ enc_len,
                          float* __restrict__ attn) {
  int b = blockIdx.x, tid = threadIdx.x;
  int len = enc_len[b];
  __shared__ float red[256];
  float v[8];
  float m = -1e30f;
#pragma unroll
  for (int i = 0; i < 8; ++i) {
    int s = tid + i * 256;
    v[i] = score[(size_t)b * SEQ + s];
    if (s < len) m = fmaxf(m, v[i]);
  }
  red[tid] = m; __syncthreads();
  for (int st = 128; st > 0; st >>= 1) {
    if (tid < st) red[tid] = fmaxf(red[tid], red[tid + st]);
    __syncthreads();
  }
  float mx = red[0]; __syncthreads();
  float sum = 0.0f;
#pragma unroll
  for (int i = 0; i < 8; ++i) {
    int s = tid + i * 256;
    float e = (s < len) ? __expf(v[i] - mx) : 0.0f;
    v[i] = e; sum += e;
  }
  red[tid] = sum; __syncthreads();
  for (int st = 128; st > 0; st >>= 1) {
    if (tid < st) red[tid] += red[tid + st];
    __syncthreads();
  }
  float inv = 1.0f / red[0];
#pragma unroll
  for (int i = 0; i < 8; ++i)
    attn[(size_t)b * SEQ + tid + i * 256] = v[i] * inv;
}

// ---------------------------------------------------------------------------
// Kernel 5: ctx[b][e] += sum_s attn[b][s] * enc[b][s][e]   (memory-bound)
// 32-row chunks, manual 8x unroll (8 float4 + 8 scalar loads in flight).
// ---------------------------------------------------------------------------
__global__ void k_context(const float* __restrict__ enc, const float* __restrict__ attn,
                          const int* __restrict__ enc_len, float* __restrict__ ctx) {
  int b = blockIdx.y, sc = blockIdx.x;   // 64 chunks of 32 rows
  int len = enc_len[b];
  int s0 = sc * 32;
  if (s0 >= len) return;
  int cnt = min(32, len - s0);
  int tid = threadIdx.x;
  const float* base = enc + ((size_t)b * SEQ + s0) * DIM + tid * 4;
  const float* ap   = attn + (size_t)b * SEQ + s0;
  float a0 = 0.f, a1 = 0.f, a2 = 0.f, a3 = 0.f;
  int i = 0;
  for (; i + 8 <= cnt; i += 8) {
    float4 x[8];
    float  w[8];
#pragma unroll
    for (int u = 0; u < 8; ++u)
      x[u] = *(const float4*)(base + (size_t)(i + u) * DIM);
#pragma unroll
    for (int u = 0; u < 8; ++u)
      w[u] = ap[i + u];
#pragma unroll
    for (int u = 0; u < 8; ++u) {
      a0 = fmaf(w[u], x[u].x, a0); a1 = fmaf(w[u], x[u].y, a1);
      a2 = fmaf(w[u], x[u].z, a2); a3 = fmaf(w[u], x[u].w, a3);
    }
  }
  for (; i < cnt; ++i) {
    float w = ap[i];
    float4 x = *(const float4*)(base + (size_t)i * DIM);
    a0 = fmaf(w, x.x, a0); a1 = fmaf(w, x.y, a1);
    a2 = fmaf(w, x.z, a2); a3 = fmaf(w, x.w, a3);
  }
  float* c = ctx + (size_t)b * DIM + tid * 4;
  atomicAdd(c + 0, a0); atomicAdd(c + 1, a1);
  atomicAdd(c + 2, a2); atomicAdd(c + 3, a3);
}

// ---------------------------------------------------------------------------
// Kernel 6: out[b][o] += ctx[b, z-chunk] @ W_out[z-chunk, o]
// 8 batches/block (grid 4 x 4 x 8) so W_out is read 4x, not 32x.
// ---------------------------------------------------------------------------
__global__ void k_out(const float* __restrict__ ctx, const float* __restrict__ W_out,
                      const float* __restrict__ b_out, float* __restrict__ out) {
  int o  = blockIdx.x * 256 + threadIdx.x;
  int bg = blockIdx.y * 8;
  int z  = blockIdx.z;
  float bias = (z == 0) ? b_out[o] : 0.0f;
  float acc[8];
#pragma unroll
  for (int j = 0; j < 8; ++j) acc[j] = bias;
  const float* wc = W_out + (size_t)z * 128 * DIM + o;
#pragma unroll 4
  for (int e = 0; e < 128; ++e) {
    float w = wc[(size_t)e * DIM];
#pragma unroll
    for (int j = 0; j < 8; ++j)
      acc[j] = fmaf(ctx[(size_t)(bg + j) * DIM + z * 128 + e], w, acc[j]);
  }
#pragma unroll
  for (int j = 0; j < 8; ++j)
    atomicAdd(&out[(size_t)(bg + j) * DIM + o], acc[j]);
}

// ---------------------------------------------------------------------------
extern "C" void kernel_launch(void* const* d_in, const int* in_sizes, int n_in,
                              void* d_out, int out_size, void* d_ws, size_t ws_size,
                              hipStream_t stream) {
  (void)in_sizes; (void)n_in; (void)out_size; (void)ws_size;
  const float* enc_states = (const float*)d_in[0];   // [32,2048,1024]
  const float* dec_states = (const float*)d_in[1];   // [32,1024]
  const float* W_enc      = (const float*)d_in[2];   // [1024,1024]
  const float* b_enc      = (const float*)d_in[3];   // [1024]
  const float* W_dec      = (const float*)d_in[4];   // [1024,1024]
  const float* b_dec      = (const float*)d_in[5];   // [1024]
  const float* w_attn     = (const float*)d_in[6];   // [1024]
  const float* W_out      = (const float*)d_in[7];   // [1024,1024]
  const float* b_out      = (const float*)d_in[8];   // [1024]
  const int*   enc_len    = (const int*)  d_in[9];   // [32]

  float* out_ctx  = (float*)d_out;                   // [32,1024]
  float* out_attn = (float*)d_out + BATCH * DIM;     // [32,2048]

  // workspace layout (3 MB used; harness provides 1 GiB and re-poisons it
  // each iteration -- the 160 us fillBuffer in the profile):
  //   Wt    @ 0        : 2 MB   (bf16 W_enc^T)
  //   score @ 2 MB     : 256 KB (zeroed)
  //   ctx   @ 2.25 MB  : 128 KB (zeroed)
  //   dech  @ 2.375 MB : 128 KB (zeroed)
  char* ws = (char*)d_ws;
  unsigned short* Wt  = (unsigned short*)ws;
  float* score = (float*)(ws + (2u << 20));
  float* ctx   = (float*)(ws + (2u << 20) + 262144);
  float* dech  = (float*)(ws + (2u << 20) + 262144 + 131072);

  // zero score + ctx + dech (all atomically accumulated)
  hipMemsetAsync(ws + (2u << 20), 0, 262144 + 131072 + 131072, stream);
  // zero out_ctx (atomically accumulated by k_out)
  hipMemsetAsync(d_out, 0, (size_t)BATCH * DIM * sizeof(float), stream);

  k_prep<<<1152, 256, 0, stream>>>(W_enc, Wt, dec_states, W_dec, b_dec, b_enc, dech);
  k_gemm256<<<1024, 512, 0, stream>>>(enc_states, Wt, dech, w_attn, enc_len, score);
  k_softmax<<<BATCH, 256, 0, stream>>>(score, enc_len, out_attn);
  k_context<<<dim3(64, BATCH), 256, 0, stream>>>(enc_states, out_attn, enc_len, ctx);
  k_out<<<dim3(4, 4, 8), 256, 0, stream>>>(ctx, W_out, b_out, out_ctx);
}

// Round 8
// 579.722 us; speedup vs baseline: 1.1588x; 1.1588x over previous
//
#include <hip/hip_runtime.h>
#include <cstdint>
#include <cstddef>

// Problem constants (fixed by reference)
#define BATCH 32
#define SEQ   2048
#define DIM   1024      // ENC_D = DEC_D = ATTN_D = OUT_D = 1024
#define MROWS (BATCH*SEQ)   // 65536

typedef __attribute__((ext_vector_type(4))) float  floatx4;
typedef __attribute__((ext_vector_type(8))) short  short8;

// fp32 -> bf16 round-to-nearest-even
__device__ __forceinline__ unsigned short f2bf(float f) {
  unsigned int u = __float_as_uint(f);
  u += 0x7fffu + ((u >> 16) & 1u);
  return (unsigned short)(u >> 16);
}

// async global->LDS, 16B per lane; LDS dest = wave-uniform base + lane*16
__device__ __forceinline__ void async16(const void* g, void* l) {
  __builtin_amdgcn_global_load_lds(
      (const __attribute__((address_space(1))) unsigned int*)g,
      (__attribute__((address_space(3))) unsigned int*)l, 16, 0, 0);
}

__device__ __forceinline__ float fast_tanh(float x) {
  float e = __expf(2.0f * x);
  return 1.0f - 2.0f * __builtin_amdgcn_rcpf(1.0f + e);
}

// ---------------------------------------------------------------------------
// Kernel P: fused prep = transpose + dech + convert in ONE launch (R6 form).
//   [0,1024)    : Wt[n][k] = bf16(W_enc[k][n])
//   [1024,1152) : dech[b][a] += dec[b]z @ W_dec z (8 batches/block, splitK x8)
//   [1152,9344) : Abf = bf16(enc_states), rows >= len skipped
// ---------------------------------------------------------------------------
__global__ void k_prep(const float* __restrict__ enc, const int* __restrict__ enc_len,
                       unsigned short* __restrict__ Abf,
                       const float* __restrict__ W_enc, unsigned short* __restrict__ Wt,
                       const float* __restrict__ dec, const float* __restrict__ W_dec,
                       const float* __restrict__ b_dec, const float* __restrict__ b_enc,
                       float* __restrict__ dech) {
  __shared__ float tile[32][33];
  int blk = blockIdx.x;
  int tid = threadIdx.x;
  if (blk < 1024) {
    // ---- transpose W_enc -> Wt (32x32 tiles) ----
    int n0 = (blk & 31) * 32, k0 = (blk >> 5) * 32;
    int tx = tid & 31, ty = tid >> 5;   // (32, 8)
#pragma unroll
    for (int i = 0; i < 4; ++i) {
      int y = ty + i * 8;
      tile[y][tx] = W_enc[(size_t)(k0 + y) * DIM + n0 + tx];
    }
    __syncthreads();
#pragma unroll
    for (int i = 0; i < 4; ++i) {
      int y = ty + i * 8;
      Wt[(size_t)(n0 + y) * DIM + k0 + tx] = f2bf(tile[tx][y]);
    }
  } else if (blk < 1152) {
    // ---- dech: 8 batches/block, split-K x8; z==0 adds biases ----
    int db = blk - 1024;
    int ax = db & 3, bgi = (db >> 2) & 3, z = db >> 4;
    int a  = ax * 256 + tid;
    int bg = bgi * 8;
    float bias = (z == 0) ? (b_dec[a] + b_enc[a]) : 0.0f;
    float acc[8];
#pragma unroll
    for (int j = 0; j < 8; ++j) acc[j] = bias;
    const float* wcp = W_dec + (size_t)z * 128 * DIM + a;
#pragma unroll 4
    for (int e = 0; e < 128; ++e) {
      float w = wcp[(size_t)e * DIM];
#pragma unroll
      for (int j = 0; j < 8; ++j)
        acc[j] = fmaf(dec[(size_t)(bg + j) * DIM + z * 128 + e], w, acc[j]);
    }
#pragma unroll
    for (int j = 0; j < 8; ++j)
      atomicAdd(&dech[(size_t)(bg + j) * DIM + a], acc[j]);
  } else {
    // ---- convert: Abf = bf16(enc), 8 rows/block, skip masked row-chunks ----
    int cv = blk - 1152;
    int b = cv >> 8, rc = cv & 255;
    int r0 = rc * 8;
    if (r0 >= enc_len[b]) return;
    size_t base = ((size_t)b * SEQ + r0) * DIM;
    const float4* src = (const float4*)(enc + base);
    ushort4* dst = (ushort4*)(Abf + base);
#pragma unroll
    for (int i = 0; i < 8; ++i) {
      float4 v = src[tid + i * 256];
      ushort4 h;
      h.x = f2bf(v.x); h.y = f2bf(v.y); h.z = f2bf(v.z); h.w = f2bf(v.w);
      dst[tid + i * 256] = h;
    }
  }
}

// ---------------------------------------------------------------------------
// Kernel 3: PERSISTENT 256x256-tile 8-phase GEMM + tanh-dot epilogue.
//   score[m] += sum_n tanh( (Abf@Wt^T)[m][n] + dech[b(m)][n] ) * w_attn[n]
//
// R8 PERSISTENT PACKING: grid = 256 blocks (1/CU, ONE round -- m201's
// packing). Block bid owns row-panel rt=bid and iterates ALL 4 nb column
// tiles as one continuous pipeline of 64 virtual tiles v (nb=v>>4, kt=v&15).
// One prologue per block (was 4), zero inter-block gaps (128KB LDS means
// consecutive blocks could never overlap anyway). TILE_STEP schedule is the
// verified R6 code; staging indexes tile v+2 (A off = (v&15)*128 bytes,
// B off = (v>>4)*524288 + (v&15)*128). Wait invariant (entering tile v:
// [B(v+1),A(v+1)] = 8 outstanding; ph4 VMCNT(8) retires them, leaves
// L(v+2)) carries over verbatim. Per-nb epilogue at v&15==15 (no barriers;
// its dech/w_attn loads imply a vmcnt drain 3x/block -- accepted ~0.5us).
// A re-reads per nb come from L3 (100MB < 256MB). ~23% of blocks masked-exit
// (len in [1024,2048]); active blocks all do identical work (balanced).
// LDS 128 KB; swizzle physical = logical ^ (((logical>>7)&7)<<4).
// ---------------------------------------------------------------------------
#define PH_BAR do { asm volatile("" ::: "memory"); __builtin_amdgcn_s_barrier(); asm volatile("" ::: "memory"); } while(0)
#define SCHED0 __builtin_amdgcn_sched_barrier(0)
#define SP1 __builtin_amdgcn_s_setprio(1)
#define SP0 __builtin_amdgcn_s_setprio(0)
#define VMCNT(n) asm volatile("s_waitcnt vmcnt(" #n ")" ::: "memory")

__global__ void __launch_bounds__(512, 2) k_gemm256(
    const unsigned short* __restrict__ Abf, // [65536,1024] bf16
    const unsigned short* __restrict__ Wt,  // [1024 n][1024 k] bf16
    const float* __restrict__ dech,         // [32,1024]
    const float* __restrict__ w_attn,       // [1024]
    const int* __restrict__ enc_len,        // [32]
    float* __restrict__ score)              // [65536], pre-zeroed
{
  int rt = blockIdx.x;                  // 256 blocks: rt = row tile 0..255
  int bb = rt >> 3;                     // batch (8 row-tiles per batch)
  int len = enc_len[bb];
  if (((rt & 7) * 256) >= len) return;  // fully masked row-panel

  __shared__ __align__(16) char lds[131072];

  int tid = threadIdx.x;
  int w = tid >> 6, lane = tid & 63;
  int wr = w >> 2;               // 0..1  M-warp
  int wc = w & 3;                // 0..3  N-warp
  int li = lane & 15, g = lane >> 4;
  int xl = (li & 7) << 4;        // lane-constant read swizzle

  const char* Ag = (const char*)(Abf + (size_t)rt * 256 * DIM);
  const char* Bg = (const char*)Wt;

  // pre-swizzled stage source offsets, collapsed to linear form
  size_t sbase = (size_t)((lane >> 3) * 2048 +
                 (((lane & 7) << 4) ^ (((lane >> 3) & 7) << 4)));
  size_t swoff = (size_t)(w * 2) * 16384;   // i adds 16384; h adds 262144
  int    ldbase = w * 2048;                 // wave-uniform LDS dest

// V = virtual tile index (nb = V>>4, kt = V&15)
#define STAGE_A(buf, h, V) do { \
  size_t ka_ = (size_t)((V) & 15) * 128; \
  async16(Ag + sbase + swoff + (size_t)(h) * 262144 + ka_, \
          lds + (buf) * 32768 + ldbase + (h) * 16384); \
  async16(Ag + sbase + swoff + 16384 + (size_t)(h) * 262144 + ka_, \
          lds + (buf) * 32768 + ldbase + 1024 + (h) * 16384); \
} while (0)
#define STAGE_B(buf, h, V) do { \
  size_t kb_ = (size_t)((V) >> 4) * 524288 + (size_t)((V) & 15) * 128; \
  async16(Bg + kb_ + sbase + swoff + (size_t)(h) * 262144, \
          lds + 65536 + (buf) * 32768 + ldbase + (h) * 16384); \
  async16(Bg + kb_ + sbase + swoff + 16384 + (size_t)(h) * 262144, \
          lds + 65536 + (buf) * 32768 + ldbase + 1024 + (h) * 16384); \
} while (0)

  short8 sA0[2][2], sA1[2][2];   // rotating A f01 / B1 slots
  short8 aX[2][2];               // A high frag-pair of current half
  short8 bX[2][2];               // B0
  floatx4 acc[8][4] = {};        // 8 m-frags x 4 n-frags

#define RD_A2(buf, f0, DST) do { \
  const char* base_ = lds + (buf) * 32768 + (wr * 128 + (f0) * 16 + li) * 128; \
  int c0_ = (g * 16) ^ xl; \
  _Pragma("unroll") for (int j = 0; j < 2; ++j) { \
    DST[j][0] = *(const short8*)(base_ + j * 2048 + c0_); \
    DST[j][1] = *(const short8*)(base_ + j * 2048 + (c0_ ^ 64)); \
  } \
} while (0)
#define RD_B(buf, nh, DST) do { \
  const char* base_ = lds + 65536 + (buf) * 32768 + (wc * 64 + (nh) * 32 + li) * 128; \
  int c0_ = (g * 16) ^ xl; \
  _Pragma("unroll") for (int tnq = 0; tnq < 2; ++tnq) { \
    DST[tnq][0] = *(const short8*)(base_ + tnq * 2048 + c0_); \
    DST[tnq][1] = *(const short8*)(base_ + tnq * 2048 + (c0_ ^ 64)); \
  } \
} while (0)
#define MFMA_Q(mh, nh, ALO, AHI, BB) do { \
  _Pragma("unroll") for (int ks = 0; ks < 2; ++ks) \
  _Pragma("unroll") for (int tnq = 0; tnq < 2; ++tnq) { \
    acc[(mh)*4+0][(nh)*2+tnq] = __builtin_amdgcn_mfma_f32_16x16x32_bf16(ALO[0][ks], BB[tnq][ks], acc[(mh)*4+0][(nh)*2+tnq], 0, 0, 0); \
    acc[(mh)*4+1][(nh)*2+tnq] = __builtin_amdgcn_mfma_f32_16x16x32_bf16(ALO[1][ks], BB[tnq][ks], acc[(mh)*4+1][(nh)*2+tnq], 0, 0, 0); \
    acc[(mh)*4+2][(nh)*2+tnq] = __builtin_amdgcn_mfma_f32_16x16x32_bf16(AHI[0][ks], BB[tnq][ks], acc[(mh)*4+2][(nh)*2+tnq], 0, 0, 0); \
    acc[(mh)*4+3][(nh)*2+tnq] = __builtin_amdgcn_mfma_f32_16x16x32_bf16(AHI[1][ks], BB[tnq][ks], acc[(mh)*4+3][(nh)*2+tnq], 0, 0, 0); \
  } \
} while (0)

// MODE 0: steady (stage tile V2, VMCNT(8) at ph4).
// MODE 1: tile 62 (no staging, VMCNT(0) at ph4).  MODE 2: tile 63 (nothing).
#define TILE_STEP(CUR, V2, MODE, SP_, SQ_) do { \
  RD_A2(CUR, 2, aX); \
  RD_B(CUR, 0, bX); \
  PH_BAR; SCHED0; SP1; MFMA_Q(0, 0, SP_, aX, bX); SP0; SCHED0; \
  PH_BAR; \
  RD_B(CUR, 1, SQ_); \
  PH_BAR; SCHED0; SP1; MFMA_Q(0, 1, SP_, aX, SQ_); SP0; SCHED0; \
  PH_BAR; \
  if ((MODE) == 0) { STAGE_B(CUR, 0, V2); STAGE_B(CUR, 1, V2); } \
  RD_A2(CUR, 4, SP_); \
  RD_A2(CUR, 6, aX); \
  PH_BAR; SCHED0; SP1; MFMA_Q(1, 1, SP_, aX, SQ_); SP0; SCHED0; \
  PH_BAR; \
  if ((MODE) == 0) { STAGE_A(CUR, 0, V2); STAGE_A(CUR, 1, V2); } \
  if ((MODE) == 0) { VMCNT(8); } else if ((MODE) == 1) { VMCNT(0); } \
  if ((MODE) < 2) RD_A2((CUR) ^ 1, 0, SQ_); \
  PH_BAR; SCHED0; SP1; MFMA_Q(1, 0, SP_, aX, bX); SP0; SCHED0; \
  PH_BAR; \
} while (0)

// per-nb epilogue: C/D layout col=lane&15 (n), row=(lane>>4)*4+reg (m) [m89]
// NB may be runtime (address arithmetic only -- no runtime reg-array index).
#define EPI(NB) do { \
  float dh_[4], wa_[4]; \
  _Pragma("unroll") for (int tn = 0; tn < 4; ++tn) { \
    int n_ = (NB) * 256 + wc * 64 + tn * 16 + li; \
    dh_[tn] = dech[(size_t)bb * DIM + n_]; \
    wa_[tn] = w_attn[n_]; \
  } \
  _Pragma("unroll") for (int tm = 0; tm < 8; ++tm) { \
    int mrow_ = rt * 256 + wr * 128 + tm * 16 + g * 4; \
    _Pragma("unroll") for (int r = 0; r < 4; ++r) { \
      float v_ = 0.0f; \
      _Pragma("unroll") for (int tn = 0; tn < 4; ++tn) \
        v_ = fmaf(wa_[tn], fast_tanh(acc[tm][tn][r] + dh_[tn]), v_); \
      v_ += __shfl_xor(v_, 1); \
      v_ += __shfl_xor(v_, 2); \
      v_ += __shfl_xor(v_, 4); \
      v_ += __shfl_xor(v_, 8); \
      if (li == 0) atomicAdd(&score[mrow_ + r], v_); \
    } \
  } \
  _Pragma("unroll") for (int tm = 0; tm < 8; ++tm) \
  _Pragma("unroll") for (int tn = 0; tn < 4; ++tn) \
  _Pragma("unroll") for (int r = 0; r < 4; ++r) \
    acc[tm][tn][r] = 0.0f; \
} while (0)

  // prologue: v0 -> buf0, v1 -> buf1 (8 loads each); VMCNT(8) retires v0,
  // leaves v1 in flight (steady invariant [B(v+1),A(v+1)]).
  STAGE_B(0, 0, 0); STAGE_B(0, 1, 0); STAGE_A(0, 0, 0); STAGE_A(0, 1, 0);
  STAGE_B(1, 0, 1); STAGE_B(1, 1, 1); STAGE_A(1, 0, 1); STAGE_A(1, 1, 1);
  VMCNT(8);
  PH_BAR;
  RD_A2(0, 0, sA0);   // tile0 f01

  // main: virtual tiles 0..61 stage tiles 2..63; epilogue at each nb boundary
#pragma unroll 1
  for (int v = 0; v < 62; v += 2) {
    TILE_STEP(0, v + 2, 0, sA0, sA1);
    TILE_STEP(1, v + 3, 0, sA1, sA0);
    if ((v & 15) == 14) {        // tiles v, v+1 = kt 14,15 of nb = v>>4
      EPI(v >> 4);               // nb 0,1,2 (v = 14, 30, 46)
    }
  }
  TILE_STEP(0, 0, 1, sA0, sA1);  // v=62
  TILE_STEP(1, 0, 2, sA1, sA0);  // v=63
  EPI(3);

#undef EPI
#undef TILE_STEP
#undef MFMA_Q
#undef RD_B
#undef RD_A2
#undef STAGE_B
#undef STAGE_A
}

// ---------------------------------------------------------------------------
// Kernel 4: masked softmax per batch row. SCALING == 1.0 (folded out).
// ---------------------------------------------------------------------------
__global__ void k_softmax(const float* __restrict__ score, const int* __restrict__ enc_len,
                          float* __restrict__ attn) {
  int b = blockIdx.x, tid = threadIdx.x;
  int len = enc_len[b];
  __shared__ float red[256];
  float v[8];
  float m = -1e30f;
#pragma unroll
  for (int i = 0; i < 8; ++i) {
    int s = tid + i * 256;
    v[i] = score[(size_t)b * SEQ + s];
    if (s < len) m = fmaxf(m, v[i]);
  }
  red[tid] = m; __syncthreads();
  for (int st = 128; st > 0; st >>= 1) {
    if (tid < st) red[tid] = fmaxf(red[tid], red[tid + st]);
    __syncthreads();
  }
  float mx = red[0]; __syncthreads();
  float sum = 0.0f;
#pragma unroll
  for (int i = 0; i < 8; ++i) {
    int s = tid + i * 256;
    float e = (s < len) ? __expf(v[i] - mx) : 0.0f;
    v[i] = e; sum += e;
  }
  red[tid] = sum; __syncthreads();
  for (int st = 128; st > 0; st >>= 1) {
    if (tid < st) red[tid] += red[tid + st];
    __syncthreads();
  }
  float inv = 1.0f / red[0];
#pragma unroll
  for (int i = 0; i < 8; ++i)
    attn[(size_t)b * SEQ + tid + i * 256] = v[i] * inv;
}

// ---------------------------------------------------------------------------
// Kernel 5: ctx[b][e] += sum_s attn[b][s] * enc[b][s][e]   (memory-bound)
// 32-row chunks, manual 8x unroll (8 float4 + 8 scalar loads in flight).
// ---------------------------------------------------------------------------
__global__ void k_context(const float* __restrict__ enc, const float* __restrict__ attn,
                          const int* __restrict__ enc_len, float* __restrict__ ctx) {
  int b = blockIdx.y, sc = blockIdx.x;   // 64 chunks of 32 rows
  int len = enc_len[b];
  int s0 = sc * 32;
  if (s0 >= len) return;
  int cnt = min(32, len - s0);
  int tid = threadIdx.x;
  const float* base = enc + ((size_t)b * SEQ + s0) * DIM + tid * 4;
  const float* ap   = attn + (size_t)b * SEQ + s0;
  float a0 = 0.f, a1 = 0.f, a2 = 0.f, a3 = 0.f;
  int i = 0;
  for (; i + 8 <= cnt; i += 8) {
    float4 x[8];
    float  w[8];
#pragma unroll
    for (int u = 0; u < 8; ++u)
      x[u] = *(const float4*)(base + (size_t)(i + u) * DIM);
#pragma unroll
    for (int u = 0; u < 8; ++u)
      w[u] = ap[i + u];
#pragma unroll
    for (int u = 0; u < 8; ++u) {
      a0 = fmaf(w[u], x[u].x, a0); a1 = fmaf(w[u], x[u].y, a1);
      a2 = fmaf(w[u], x[u].z, a2); a3 = fmaf(w[u], x[u].w, a3);
    }
  }
  for (; i < cnt; ++i) {
    float w = ap[i];
    float4 x = *(const float4*)(base + (size_t)i * DIM);
    a0 = fmaf(w, x.x, a0); a1 = fmaf(w, x.y, a1);
    a2 = fmaf(w, x.z, a2); a3 = fmaf(w, x.w, a3);
  }
  float* c = ctx + (size_t)b * DIM + tid * 4;
  atomicAdd(c + 0, a0); atomicAdd(c + 1, a1);
  atomicAdd(c + 2, a2); atomicAdd(c + 3, a3);
}

// ---------------------------------------------------------------------------
// Kernel 6: out[b][o] += ctx[b, z-chunk] @ W_out[z-chunk, o]
// 8 batches/block (grid 4 x 4 x 8) so W_out is read 4x, not 32x.
// ---------------------------------------------------------------------------
__global__ void k_out(const float* __restrict__ ctx, const float* __restrict__ W_out,
                      const float* __restrict__ b_out, float* __restrict__ out) {
  int o  = blockIdx.x * 256 + threadIdx.x;
  int bg = blockIdx.y * 8;
  int z  = blockIdx.z;
  float bias = (z == 0) ? b_out[o] : 0.0f;
  float acc[8];
#pragma unroll
  for (int j = 0; j < 8; ++j) acc[j] = bias;
  const float* wc = W_out + (size_t)z * 128 * DIM + o;
#pragma unroll 4
  for (int e = 0; e < 128; ++e) {
    float w = wc[(size_t)e * DIM];
#pragma unroll
    for (int j = 0; j < 8; ++j)
      acc[j] = fmaf(ctx[(size_t)(bg + j) * DIM + z * 128 + e], w, acc[j]);
  }
#pragma unroll
  for (int j = 0; j < 8; ++j)
    atomicAdd(&out[(size_t)(bg + j) * DIM + o], acc[j]);
}

// ---------------------------------------------------------------------------
extern "C" void kernel_launch(void* const* d_in, const int* in_sizes, int n_in,
                              void* d_out, int out_size, void* d_ws, size_t ws_size,
                              hipStream_t stream) {
  (void)in_sizes; (void)n_in; (void)out_size; (void)ws_size;
  const float* enc_states = (const float*)d_in[0];   // [32,2048,1024]
  const float* dec_states = (const float*)d_in[1];   // [32,1024]
  const float* W_enc      = (const float*)d_in[2];   // [1024,1024]
  const float* b_enc      = (const float*)d_in[3];   // [1024]
  const float* W_dec      = (const float*)d_in[4];   // [1024,1024]
  const float* b_dec      = (const float*)d_in[5];   // [1024]
  const float* w_attn     = (const float*)d_in[6];   // [1024]
  const float* W_out      = (const float*)d_in[7];   // [1024,1024]
  const float* b_out      = (const float*)d_in[8];   // [1024]
  const int*   enc_len    = (const int*)  d_in[9];   // [32]

  float* out_ctx  = (float*)d_out;                   // [32,1024]
  float* out_attn = (float*)d_out + BATCH * DIM;     // [32,2048]

  // workspace layout (harness ws is 1 GiB, re-poisoned each iteration --
  // the ~160 us fillBuffer visible in the profile):
  //   Wt    @ 0        : 2 MB   (bf16 W_enc^T)
  //   score @ 2 MB     : 256 KB (zeroed)
  //   ctx   @ 2.25 MB  : 128 KB (zeroed)
  //   dech  @ 2.375 MB : 128 KB (zeroed)
  //   Abf   @ 3 MB     : 128 MB (bf16 enc_states)
  char* ws = (char*)d_ws;
  unsigned short* Wt  = (unsigned short*)ws;
  float* score = (float*)(ws + (2u << 20));
  float* ctx   = (float*)(ws + (2u << 20) + 262144);
  float* dech  = (float*)(ws + (2u << 20) + 262144 + 131072);
  unsigned short* Abf = (unsigned short*)(ws + (3u << 20));

  // zero score + ctx + dech (all atomically accumulated)
  hipMemsetAsync(ws + (2u << 20), 0, 262144 + 131072 + 131072, stream);
  // zero out_ctx (atomically accumulated by k_out)
  hipMemsetAsync(d_out, 0, (size_t)BATCH * DIM * sizeof(float), stream);

  k_prep<<<9344, 256, 0, stream>>>(enc_states, enc_len, Abf,
                                   W_enc, Wt, dec_states, W_dec, b_dec, b_enc, dech);
  k_gemm256<<<256, 512, 0, stream>>>(Abf, Wt, dech, w_attn, enc_len, score);
  k_softmax<<<BATCH, 256, 0, stream>>>(score, enc_len, out_attn);
  k_context<<<dim3(64, BATCH), 256, 0, stream>>>(enc_states, out_attn, enc_len, ctx);
  k_out<<<dim3(4, 4, 8), 256, 0, stream>>>(ctx, W_out, b_out, out_ctx);
}